// Round 9
// baseline (44533.081 us; speedup 1.0000x reference)
//
#include <hip/hip_runtime.h>
#include <hip/hip_bf16.h>

constexpr int kT = 256, kB = 32, kIN = 1024, kH = 1024;
constexpr int kBH = kB * kH;  // 32768

__device__ inline float sigmoidf(float x) { return 1.f / (1.f + expf(-x)); }

// One LSTM step for one layer, pure fp32, no MFMA. Grid = 256 blocks x 128
// threads. Block = 16 batches x 8 hidden units; each thread owns ALL FOUR
// gates of one (b,u): preact[g] = x_t . W[g*kH+u] + y_{t-1} . R[g*kH+u]
// + bW[g*kH+u] + bR[g*kH+u]; then i,f,g,o nonlinearities and the c/y update
// thread-locally. A-operand staged in LDS (128-wide k-chunks, row stride 129).
__global__ __launch_bounds__(128)
void lstm_step_naive(const float* __restrict__ xA,   // [kB][1024] step input
                     const float* __restrict__ Wm,   // [4H][1024]
                     const float* __restrict__ bWv,  // [4H]
                     const float* __restrict__ bRv,  // [4H]
                     const float* __restrict__ Rm,   // [4H][1024]
                     const float* __restrict__ ysrc, // [kB][1024] y_{t-1}
                     float* __restrict__ ydst,       // [kB][1024] y_t
                     float* __restrict__ cst) {      // [kB][1024] cell, in-place
    const int tid = threadIdx.x;
    const int b0 = (blockIdx.x & 1) << 4;          // batch half: 0 or 16
    const int bl = tid & 15;                       // local batch row
    const int b  = b0 + bl;
    const int u  = ((blockIdx.x >> 1) << 3) + (tid >> 4);  // hidden unit

    __shared__ float As[16][129];
    float acc[4] = {0.f, 0.f, 0.f, 0.f};

    const float* wrow[4];
#pragma unroll
    for (int g = 0; g < 4; g++) wrow[g] = Wm + (size_t)(g * kH + u) * 1024;

    // ---- phase 1: input projection over xA ----
    for (int k0 = 0; k0 < 1024; k0 += 128) {
        __syncthreads();
        for (int i = tid; i < 16 * 128; i += 128)
            As[i >> 7][i & 127] = xA[(size_t)(b0 + (i >> 7)) * 1024 + k0 + (i & 127)];
        __syncthreads();
#pragma unroll 4
        for (int k = 0; k < 128; k += 4) {
            const float a0 = As[bl][k],     a1 = As[bl][k + 1];
            const float a2 = As[bl][k + 2], a3 = As[bl][k + 3];
#pragma unroll
            for (int g = 0; g < 4; g++) {
                const float4 w = *reinterpret_cast<const float4*>(wrow[g] + k0 + k);
                acc[g] += a0 * w.x + a1 * w.y + a2 * w.z + a3 * w.w;
            }
        }
    }

#pragma unroll
    for (int g = 0; g < 4; g++) wrow[g] = Rm + (size_t)(g * kH + u) * 1024;

    // ---- phase 2: recurrent matmul over ysrc ----
    for (int k0 = 0; k0 < 1024; k0 += 128) {
        __syncthreads();
        for (int i = tid; i < 16 * 128; i += 128)
            As[i >> 7][i & 127] = ysrc[(size_t)(b0 + (i >> 7)) * 1024 + k0 + (i & 127)];
        __syncthreads();
#pragma unroll 4
        for (int k = 0; k < 128; k += 4) {
            const float a0 = As[bl][k],     a1 = As[bl][k + 1];
            const float a2 = As[bl][k + 2], a3 = As[bl][k + 3];
#pragma unroll
            for (int g = 0; g < 4; g++) {
                const float4 w = *reinterpret_cast<const float4*>(wrow[g] + k0 + k);
                acc[g] += a0 * w.x + a1 * w.y + a2 * w.z + a3 * w.w;
            }
        }
    }

    // ---- gates + state update (gate order i,f,g,o) ----
#pragma unroll
    for (int g = 0; g < 4; g++) acc[g] += bWv[g * kH + u] + bRv[g * kH + u];
    const float iv = sigmoidf(acc[0]);
    const float fv = sigmoidf(acc[1]);
    const float gv = tanhf(acc[2]);
    const float ov = sigmoidf(acc[3]);
    const size_t off = (size_t)b * kH + u;
    const float c = fv * cst[off] + iv * gv;
    const float y = ov * tanhf(c);
    cst[off] = c;
    ydst[off] = y;
}

// h_n = [y1[T-1] (from ws), y2[T-1] (already in out)]; c_n = cst. All fp32.
__global__ void finalize(const float* __restrict__ y1last,
                         const float* __restrict__ cst,
                         float* __restrict__ out) {
    const int idx = blockIdx.x * blockDim.x + threadIdx.x;
    if (idx >= 2 * kBH) return;
    const float hv = (idx < kBH) ? y1last[idx]
                                 : out[(size_t)(kT - 1) * kBH + (idx - kBH)];
    out[(size_t)kT * kBH + idx] = hv;
    out[(size_t)kT * kBH + 2 * kBH + idx] = cst[idx];
}

extern "C" void kernel_launch(void* const* d_in, const int* in_sizes, int n_in,
                              void* d_out, int out_size, void* d_ws, size_t ws_size,
                              hipStream_t stream) {
    (void)in_sizes; (void)n_in; (void)out_size; (void)ws_size;
    // Confirmed by round-7/8 probes: inputs fp32 in documented (insertion)
    // order; d_out is fp32 (y2 | h_n | c_n flat).
    const float* x   = (const float*)d_in[0];
    const float* h0  = (const float*)d_in[1];
    const float* c0  = (const float*)d_in[2];
    const float* W0  = (const float*)d_in[3];
    const float* R0  = (const float*)d_in[4];
    const float* bW0 = (const float*)d_in[5];
    const float* bR0 = (const float*)d_in[6];
    const float* W1  = (const float*)d_in[7];
    const float* R1  = (const float*)d_in[8];
    const float* bW1 = (const float*)d_in[9];
    const float* bR1 = (const float*)d_in[10];
    float* out = (float*)d_out;

    // ws: y1 ping-pong (2*kBH f32) | cst (2*kBH f32)  = 512 KB total
    float* y1pp = (float*)d_ws;
    float* cst  = y1pp + 2 * (size_t)kBH;

    hipMemcpyAsync(cst, c0, 2 * (size_t)kBH * sizeof(float),
                   hipMemcpyDeviceToDevice, stream);

    for (int t = 0; t < kT; t++) {
        const float* ysrc0 = t ? y1pp + (size_t)((t - 1) & 1) * kBH : h0;
        float* y1t = y1pp + (size_t)(t & 1) * kBH;
        lstm_step_naive<<<dim3(256), dim3(128), 0, stream>>>(
            x + (size_t)t * kB * kIN, W0, bW0, bR0, R0, ysrc0, y1t, cst);
        const float* ysrc1 = t ? out + (size_t)(t - 1) * kBH : h0 + kBH;
        lstm_step_naive<<<dim3(256), dim3(128), 0, stream>>>(
            y1t, W1, bW1, bR1, R1, ysrc1, out + (size_t)t * kBH, cst + kBH);
    }

    finalize<<<dim3((2 * kBH + 255) / 256), dim3(256), 0, stream>>>(
        y1pp + (size_t)((kT - 1) & 1) * kBH, cst, out);
}

// Round 10
// 8275.459 us; speedup vs baseline: 5.3813x; 5.3813x over previous
//
#include <hip/hip_runtime.h>
#include <hip/hip_bf16.h>

using bf16 = __hip_bfloat16;
typedef __attribute__((ext_vector_type(8))) short short8;   // 8 bf16 = 16B
typedef __attribute__((ext_vector_type(4))) float f32x4;

constexpr int kT = 256, kB = 32, kIN = 1024, kH = 1024, kG = 4096;
constexpr int kBH = kB * kH;  // 32768

__device__ inline f32x4 mfma16(short8 a, short8 b, f32x4 c) {
    return __builtin_amdgcn_mfma_f32_16x16x32_bf16(a, b, c, 0, 0, 0);
}
__device__ inline short8 ld8(const bf16* p) {
    return *reinterpret_cast<const short8*>(p);
}
__device__ inline float sigmoidf(float x) { return 1.f / (1.f + expf(-x)); }

// ---------- prep: fp32 -> bf16 ----------
__global__ void cvt_f32_bf16(const float* __restrict__ in,
                             bf16* __restrict__ outp, int n) {
    for (int i = blockIdx.x * blockDim.x + threadIdx.x; i < n;
         i += gridDim.x * blockDim.x)
        outp[i] = __float2bfloat16(in[i]);
}

// ---------- big GEMM: C[M,N] f32 = A[M,K]bf16 @ Bm[N,K]^T bf16 + b1+b2 ----------
// One wave per block computes a 64x64 tile via 4x4 grid of 16x16x32 MFMAs.
// Fragment mapping (verified m89/m91): A/B row = lane&15, k-chunk = (lane>>4)*8;
// D: col = lane&15, row = (lane>>4)*4 + reg.
__global__ __launch_bounds__(64)
void gemm_bias(const bf16* __restrict__ A, const bf16* __restrict__ Bm,
               const float* __restrict__ b1, const float* __restrict__ b2,
               float* __restrict__ C, int M, int N, int K) {
    const int lane = threadIdx.x;
    const int tn = N >> 6;
    const int bm = blockIdx.x / tn, bn = blockIdx.x - bm * tn;
    const int m0 = bm << 6, n0 = bn << 6;
    const int fr = lane & 15, kq = (lane >> 4) << 3;
    f32x4 acc[4][4];
#pragma unroll
    for (int i = 0; i < 4; i++)
#pragma unroll
        for (int j = 0; j < 4; j++) acc[i][j] = (f32x4){0.f, 0.f, 0.f, 0.f};
    const bf16* Ap = A + (size_t)(m0 + fr) * K + kq;
    const bf16* Bp = Bm + (size_t)(n0 + fr) * K + kq;
    for (int k = 0; k < K; k += 32) {
        short8 af[4], bfr[4];
#pragma unroll
        for (int i = 0; i < 4; i++) af[i] = ld8(Ap + (size_t)(i * 16) * K + k);
#pragma unroll
        for (int i = 0; i < 4; i++) bfr[i] = ld8(Bp + (size_t)(i * 16) * K + k);
#pragma unroll
        for (int i = 0; i < 4; i++)
#pragma unroll
            for (int j = 0; j < 4; j++)
                acc[i][j] = mfma16(af[i], bfr[j], acc[i][j]);
    }
    const int crow = (lane >> 4) << 2, ccol = lane & 15;
#pragma unroll
    for (int j = 0; j < 4; j++) {
        const int nn = n0 + j * 16 + ccol;
        const float bias = b1[nn] + b2[nn];
#pragma unroll
        for (int i = 0; i < 4; i++) {
            const int mm = m0 + i * 16 + crow;
#pragma unroll
            for (int r = 0; r < 4; r++)
                C[(size_t)(mm + r) * N + nn] = acc[i][j][r] + bias;
        }
    }
}

// ---------- MFMA LSTM step ----------
// Grid = 64 blocks x 256 threads (4 waves). Block owns 16 hidden units u0..;
// wave w computes gate w's 32x16 preact tile: [gx_t or x@W^T] + y_{t-1}@R^T;
// then block fuses the i,f,g,o nonlinearities + c/y update.
// FUSED=false: preact base comes from precomputed gx (bias already included).
// FUSED=true : adds x_t@W^T inline and bias b1+b2 in the epilogue.
template <bool FUSED>
__global__ __launch_bounds__(256)
void lstm_step_mfma(const float* __restrict__ gx,   // [kB,kG] (non-fused)
                    const bf16* __restrict__ xbf,   // [kB,1024] (fused)
                    const bf16* __restrict__ Wbf,   // [kG,1024] (fused)
                    const float* __restrict__ b1,   // [kG] (fused)
                    const float* __restrict__ b2,   // [kG] (fused)
                    const bf16* __restrict__ Rbf,   // [kG,kH]
                    const bf16* __restrict__ ysrc,  // [kB,kH] y_{t-1} bf16
                    bf16* __restrict__ ydst_bf,     // [kB,kH] y_t bf16
                    float* __restrict__ ydst_f,     // [kB,kH] y_t fp32 or null
                    float* __restrict__ cst) {      // [kB,kH] fp32, in-place
    const int lane = threadIdx.x & 63, w = threadIdx.x >> 6;
    const int u0 = blockIdx.x << 4;
    const int fr = lane & 15, kq = (lane >> 4) << 3;
    const int n = w * kH + u0;                 // gate-column base
    f32x4 acc0 = {0.f, 0.f, 0.f, 0.f}, acc1 = {0.f, 0.f, 0.f, 0.f};
    {   // recurrent: y_{t-1}[32,1024] @ R[n..n+15,:]^T
        const bf16* Bp = Rbf + (size_t)(n + fr) * kH + kq;
        const bf16* A0 = ysrc + (size_t)fr * kH + kq;
        const bf16* A1 = ysrc + (size_t)(16 + fr) * kH + kq;
#pragma unroll 4
        for (int k = 0; k < kH; k += 32) {
            short8 bfrag = ld8(Bp + k);
            short8 a0 = ld8(A0 + k);
            short8 a1 = ld8(A1 + k);
            acc0 = mfma16(a0, bfrag, acc0);
            acc1 = mfma16(a1, bfrag, acc1);
        }
    }
    if (FUSED) {  // input projection: x_t[32,1024] @ W[n..n+15,:]^T
        const bf16* Bp = Wbf + (size_t)(n + fr) * kIN + kq;
        const bf16* A0 = xbf + (size_t)fr * kIN + kq;
        const bf16* A1 = xbf + (size_t)(16 + fr) * kIN + kq;
#pragma unroll 4
        for (int k = 0; k < kIN; k += 32) {
            short8 bfrag = ld8(Bp + k);
            short8 a0 = ld8(A0 + k);
            short8 a1 = ld8(A1 + k);
            acc0 = mfma16(a0, bfrag, acc0);
            acc1 = mfma16(a1, bfrag, acc1);
        }
    }
    __shared__ float pre[4][kB][16];
    const int crow = (lane >> 4) << 2, ccol = lane & 15;
#pragma unroll
    for (int r = 0; r < 4; r++) {
        const int b = crow + r;
        float e0, e1;
        if (FUSED) {
            const float bias = b1[n + ccol] + b2[n + ccol];
            e0 = bias; e1 = bias;
        } else {
            e0 = gx[(size_t)b * kG + n + ccol];
            e1 = gx[(size_t)(b + 16) * kG + n + ccol];
        }
        pre[w][b][ccol] = acc0[r] + e0;
        pre[w][b + 16][ccol] = acc1[r] + e1;
    }
    __syncthreads();
    for (int idx = threadIdx.x; idx < kB * 16; idx += 256) {
        const int b = idx >> 4, col = idx & 15;
        const int u = u0 + col;
        const float iv = sigmoidf(pre[0][b][col]);
        const float fv = sigmoidf(pre[1][b][col]);
        const float gv = tanhf(pre[2][b][col]);
        const float ov = sigmoidf(pre[3][b][col]);
        const size_t off = (size_t)b * kH + u;
        const float c = fv * cst[off] + iv * gv;
        const float y = ov * tanhf(c);
        cst[off] = c;
        ydst_bf[off] = __float2bfloat16(y);
        if (ydst_f) ydst_f[off] = y;
    }
}

// h_n[0] = f32(y1last bf16); h_n[1] = y2[T-1] (already fp32 in out); c_n = cst.
__global__ void finalize_bf(const bf16* __restrict__ y1last,
                            const float* __restrict__ cst,
                            float* __restrict__ out) {
    const int idx = blockIdx.x * blockDim.x + threadIdx.x;
    if (idx >= 2 * kBH) return;
    const float hv = (idx < kBH)
        ? __bfloat162float(y1last[idx])
        : out[(size_t)(kT - 1) * kBH + (idx - kBH)];
    out[(size_t)kT * kBH + idx] = hv;
    out[(size_t)kT * kBH + 2 * kBH + idx] = cst[idx];
}

// ---------- round-9 naive fallback (proven correct, 512 KB ws) ----------
__global__ __launch_bounds__(128)
void lstm_step_naive(const float* __restrict__ xA, const float* __restrict__ Wm,
                     const float* __restrict__ bWv, const float* __restrict__ bRv,
                     const float* __restrict__ Rm, const float* __restrict__ ysrc,
                     float* __restrict__ ydst, float* __restrict__ cst) {
    const int tid = threadIdx.x;
    const int b0 = (blockIdx.x & 1) << 4;
    const int bl = tid & 15;
    const int b  = b0 + bl;
    const int u  = ((blockIdx.x >> 1) << 3) + (tid >> 4);
    __shared__ float As[16][129];
    float acc[4] = {0.f, 0.f, 0.f, 0.f};
    const float* wrow[4];
#pragma unroll
    for (int g = 0; g < 4; g++) wrow[g] = Wm + (size_t)(g * kH + u) * 1024;
    for (int k0 = 0; k0 < 1024; k0 += 128) {
        __syncthreads();
        for (int i = tid; i < 16 * 128; i += 128)
            As[i >> 7][i & 127] = xA[(size_t)(b0 + (i >> 7)) * 1024 + k0 + (i & 127)];
        __syncthreads();
#pragma unroll 4
        for (int k = 0; k < 128; k += 4) {
            const float a0 = As[bl][k], a1 = As[bl][k + 1];
            const float a2 = As[bl][k + 2], a3 = As[bl][k + 3];
#pragma unroll
            for (int g = 0; g < 4; g++) {
                const float4 w4 = *reinterpret_cast<const float4*>(wrow[g] + k0 + k);
                acc[g] += a0 * w4.x + a1 * w4.y + a2 * w4.z + a3 * w4.w;
            }
        }
    }
#pragma unroll
    for (int g = 0; g < 4; g++) wrow[g] = Rm + (size_t)(g * kH + u) * 1024;
    for (int k0 = 0; k0 < 1024; k0 += 128) {
        __syncthreads();
        for (int i = tid; i < 16 * 128; i += 128)
            As[i >> 7][i & 127] = ysrc[(size_t)(b0 + (i >> 7)) * 1024 + k0 + (i & 127)];
        __syncthreads();
#pragma unroll 4
        for (int k = 0; k < 128; k += 4) {
            const float a0 = As[bl][k], a1 = As[bl][k + 1];
            const float a2 = As[bl][k + 2], a3 = As[bl][k + 3];
#pragma unroll
            for (int g = 0; g < 4; g++) {
                const float4 w4 = *reinterpret_cast<const float4*>(wrow[g] + k0 + k);
                acc[g] += a0 * w4.x + a1 * w4.y + a2 * w4.z + a3 * w4.w;
            }
        }
    }
#pragma unroll
    for (int g = 0; g < 4; g++) acc[g] += bWv[g * kH + u] + bRv[g * kH + u];
    const float iv = sigmoidf(acc[0]);
    const float fv = sigmoidf(acc[1]);
    const float gv = tanhf(acc[2]);
    const float ov = sigmoidf(acc[3]);
    const size_t off = (size_t)b * kH + u;
    const float c = fv * cst[off] + iv * gv;
    const float y = ov * tanhf(c);
    cst[off] = c;
    ydst[off] = y;
}

__global__ void finalize_f32(const float* __restrict__ y1last,
                             const float* __restrict__ cst,
                             float* __restrict__ out) {
    const int idx = blockIdx.x * blockDim.x + threadIdx.x;
    if (idx >= 2 * kBH) return;
    const float hv = (idx < kBH) ? y1last[idx]
                                 : out[(size_t)(kT - 1) * kBH + (idx - kBH)];
    out[(size_t)kT * kBH + idx] = hv;
    out[(size_t)kT * kBH + 2 * kBH + idx] = cst[idx];
}

extern "C" void kernel_launch(void* const* d_in, const int* in_sizes, int n_in,
                              void* d_out, int out_size, void* d_ws, size_t ws_size,
                              hipStream_t stream) {
    (void)in_sizes; (void)n_in; (void)out_size;
    const float* x   = (const float*)d_in[0];
    const float* h0  = (const float*)d_in[1];
    const float* c0  = (const float*)d_in[2];
    const float* W0  = (const float*)d_in[3];
    const float* R0  = (const float*)d_in[4];
    const float* bW0 = (const float*)d_in[5];
    const float* bR0 = (const float*)d_in[6];
    const float* W1  = (const float*)d_in[7];
    const float* R1  = (const float*)d_in[8];
    const float* bW1 = (const float*)d_in[9];
    const float* bR1 = (const float*)d_in[10];
    float* out = (float*)d_out;
    char* wsp = (char*)d_ws;

    const size_t gxB  = (size_t)kT * kB * kG * 4;   // 134,217,728
    const size_t xbfB = (size_t)kT * kBH * 2;       //  16,777,216
    const size_t wB   = (size_t)kG * kH * 2;        //   8,388,608 each
    const size_t hbfB = 2 * (size_t)kBH * 2;        //     131,072
    const size_t ppB  = 2 * (size_t)kBH * 2;        //     131,072
    const size_t cstB = 2 * (size_t)kBH * 4;        //     262,144
    const size_t needA = gxB + 2 * xbfB + 4 * wB + hbfB + ppB + cstB;  // ~202MB
    const size_t needB = xbfB + 4 * wB + hbfB + 2 * ppB + cstB;        //  ~51MB

    const dim3 cvB(256), stB(256), stG(kH / 16), fiG((2 * kBH + 255) / 256);

    if (ws_size >= needA) {
        // ---- Path A: precompute gates_x for both layers ----
        float* gx    = (float*)wsp;
        bf16*  xbf   = (bf16*)(wsp + gxB);
        bf16*  y1seq = (bf16*)(wsp + gxB + xbfB);
        bf16*  Wb0   = (bf16*)(wsp + gxB + 2 * xbfB);
        bf16*  Rb0   = (bf16*)((char*)Wb0 + wB);
        bf16*  Wb1   = (bf16*)((char*)Wb0 + 2 * wB);
        bf16*  Rb1   = (bf16*)((char*)Wb0 + 3 * wB);
        bf16*  hbf   = (bf16*)((char*)Wb0 + 4 * wB);
        bf16*  y2pp  = (bf16*)((char*)hbf + hbfB);
        float* cst   = (float*)((char*)y2pp + ppB);

        cvt_f32_bf16<<<dim3(1024), cvB, 0, stream>>>(x, xbf, kT * kBH);
        cvt_f32_bf16<<<dim3(1024), cvB, 0, stream>>>(W0, Wb0, kG * kH);
        cvt_f32_bf16<<<dim3(1024), cvB, 0, stream>>>(R0, Rb0, kG * kH);
        cvt_f32_bf16<<<dim3(1024), cvB, 0, stream>>>(W1, Wb1, kG * kH);
        cvt_f32_bf16<<<dim3(1024), cvB, 0, stream>>>(R1, Rb1, kG * kH);
        cvt_f32_bf16<<<dim3(64), cvB, 0, stream>>>(h0, hbf, 2 * kBH);
        hipMemcpyAsync(cst, c0, cstB, hipMemcpyDeviceToDevice, stream);

        gemm_bias<<<dim3((kT * kB / 64) * (kG / 64)), dim3(64), 0, stream>>>(
            xbf, Wb0, bW0, bR0, gx, kT * kB, kG, kIN);
        for (int t = 0; t < kT; t++) {
            const bf16* ys = t ? y1seq + (size_t)(t - 1) * kBH : hbf;
            lstm_step_mfma<false><<<stG, stB, 0, stream>>>(
                gx + (size_t)t * kB * kG, nullptr, nullptr, nullptr, nullptr,
                Rb0, ys, y1seq + (size_t)t * kBH, nullptr, cst);
        }
        gemm_bias<<<dim3((kT * kB / 64) * (kG / 64)), dim3(64), 0, stream>>>(
            y1seq, Wb1, bW1, bR1, gx, kT * kB, kG, kH);
        for (int t = 0; t < kT; t++) {
            const bf16* ys = t ? y2pp + (size_t)((t - 1) & 1) * kBH : hbf + kBH;
            lstm_step_mfma<false><<<stG, stB, 0, stream>>>(
                gx + (size_t)t * kB * kG, nullptr, nullptr, nullptr, nullptr,
                Rb1, ys, y2pp + (size_t)(t & 1) * kBH,
                out + (size_t)t * kBH, cst + kBH);
        }
        finalize_bf<<<fiG, dim3(256), 0, stream>>>(
            y1seq + (size_t)(kT - 1) * kBH, cst, out);
    } else if (ws_size >= needB) {
        // ---- Path B: fused W-matmul per step ----
        bf16*  xbf  = (bf16*)wsp;
        bf16*  Wb0  = (bf16*)(wsp + xbfB);
        bf16*  Rb0  = (bf16*)((char*)Wb0 + wB);
        bf16*  Wb1  = (bf16*)((char*)Wb0 + 2 * wB);
        bf16*  Rb1  = (bf16*)((char*)Wb0 + 3 * wB);
        bf16*  hbf  = (bf16*)((char*)Wb0 + 4 * wB);
        bf16*  y1pp = (bf16*)((char*)hbf + hbfB);
        bf16*  y2pp = (bf16*)((char*)y1pp + ppB);
        float* cst  = (float*)((char*)y2pp + ppB);

        cvt_f32_bf16<<<dim3(1024), cvB, 0, stream>>>(x, xbf, kT * kBH);
        cvt_f32_bf16<<<dim3(1024), cvB, 0, stream>>>(W0, Wb0, kG * kH);
        cvt_f32_bf16<<<dim3(1024), cvB, 0, stream>>>(R0, Rb0, kG * kH);
        cvt_f32_bf16<<<dim3(1024), cvB, 0, stream>>>(W1, Wb1, kG * kH);
        cvt_f32_bf16<<<dim3(1024), cvB, 0, stream>>>(R1, Rb1, kG * kH);
        cvt_f32_bf16<<<dim3(64), cvB, 0, stream>>>(h0, hbf, 2 * kBH);
        hipMemcpyAsync(cst, c0, cstB, hipMemcpyDeviceToDevice, stream);

        for (int t = 0; t < kT; t++) {
            const bf16* ys0 = t ? y1pp + (size_t)((t - 1) & 1) * kBH : hbf;
            bf16* y1t = y1pp + (size_t)(t & 1) * kBH;
            lstm_step_mfma<true><<<stG, stB, 0, stream>>>(
                nullptr, xbf + (size_t)t * kBH, Wb0, bW0, bR0,
                Rb0, ys0, y1t, nullptr, cst);
            const bf16* ys1 = t ? y2pp + (size_t)((t - 1) & 1) * kBH : hbf + kBH;
            lstm_step_mfma<true><<<stG, stB, 0, stream>>>(
                nullptr, y1t, Wb1, bW1, bR1,
                Rb1, ys1, y2pp + (size_t)(t & 1) * kBH,
                out + (size_t)t * kBH, cst + kBH);
        }
        finalize_bf<<<fiG, dim3(256), 0, stream>>>(
            y1pp + (size_t)((kT - 1) & 1) * kBH, cst, out);
    } else {
        // ---- Path C: round-9 naive fp32 (proven) ----
        float* y1pp = (float*)wsp;
        float* cst  = y1pp + 2 * (size_t)kBH;
        hipMemcpyAsync(cst, c0, cstB, hipMemcpyDeviceToDevice, stream);
        for (int t = 0; t < kT; t++) {
            const float* ys0 = t ? y1pp + (size_t)((t - 1) & 1) * kBH : h0;
            float* y1t = y1pp + (size_t)(t & 1) * kBH;
            lstm_step_naive<<<dim3(256), dim3(128), 0, stream>>>(
                x + (size_t)t * kB * kIN, W0, bW0, bR0, R0, ys0, y1t, cst);
            const float* ys1 = t ? out + (size_t)(t - 1) * kBH : h0 + kBH;
            lstm_step_naive<<<dim3(256), dim3(128), 0, stream>>>(
                y1t, W1, bW1, bR1, R1, ys1, out + (size_t)t * kBH, cst + kBH);
        }
        finalize_f32<<<fiG, dim3(256), 0, stream>>>(
            y1pp + (size_t)((kT - 1) & 1) * kBH, cst, out);
    }
}